// Round 1
// baseline (300.692 us; speedup 1.0000x reference)
//
#include <hip/hip_runtime.h>

// ---------------- workspace layout (floats) ----------------
// 5 matrices stored in "a-quad, lane, 4" packed layout:
//   ws[m*4096 + (a>>2)*256 + c*4 + (a&3)] = M_m[a][c]
// m: 0=A_qk(WqWk^T) 1=G_q 2=G_k 3=G_v 4=M_vo(Wv@Wo)
#define WS_PQ  20480   // Wq@bk [64]
#define WS_PK  20544   // Wk@bq [64]
#define WS_UQ  20608   // Wq@bq
#define WS_UK  20672   // Wk@bk
#define WS_UV  20736   // Wv@bv
#define WS_RVO 20800   // bv@Wo [64]
#define WS_SC  20864   // c0=bq.bk, sq=|bq|^2, sk, sv
#define WS_PE  20992   // pe[16][64]

#define XPAD 68          // floats per xs row (16B-aligned, 64 used)
#define XSTRIDE 1092     // per-pixel xs stride (16*XPAD+4: breaks flush bank aliasing)
#define SPAD 72          // ushorts per scr row (16B-aligned quads)

__device__ __forceinline__ unsigned short f2bf(float f) {
  unsigned u = __float_as_uint(f);
  u += 0x7fffu + ((u >> 16) & 1u);          // RNE round to bf16
  return (unsigned short)(u >> 16);
}
__device__ __forceinline__ float bfl(unsigned u) { return __uint_as_float(u << 16); }
__device__ __forceinline__ float bfh(unsigned u) { return __uint_as_float(u & 0xffff0000u); }
__device__ __forceinline__ uint4 ld_su4(const unsigned short* p) {
  uint4 r; __builtin_memcpy(&r, (const void*)p, 16); return r;
}

// ---------------- K1a: five 64x64 matrices ----------------
__global__ __launch_bounds__(256) void k1_mats(
    const float* __restrict__ Wq, const float* __restrict__ Wk,
    const float* __restrict__ Wv, const float* __restrict__ Wo,
    float* __restrict__ ws)
{
  __shared__ float Ls[8][129];
  __shared__ float Rs[64][129];
  const int m  = blockIdx.x >> 3;           // matrix id
  const int a0 = (blockIdx.x & 7) * 8;      // 8-row tile
  const int t  = threadIdx.x;
  const int b  = t & 63, ag = t >> 6;
  const float* L = (m <= 1) ? Wq : (m == 2) ? Wk : Wv;
  const float* R = (m == 0 || m == 2) ? Wk : (m == 1) ? Wq : Wv;  // m==4 special
  float acc0 = 0.f, acc1 = 0.f;
  for (int dc = 0; dc < 4; ++dc) {
    __syncthreads();
#pragma unroll
    for (int k = 0; k < 4; ++k) {
      int idx = t + k * 256, row = idx >> 7, col = idx & 127;
      Ls[row][col] = L[(a0 + row) * 512 + dc * 128 + col];
    }
    if (m < 4) {
#pragma unroll
      for (int k = 0; k < 32; ++k) {
        int idx = t + k * 256, row = idx >> 7, col = idx & 127;
        Rs[row][col] = R[row * 512 + dc * 128 + col];
      }
    } else {  // R side is Wo^T: Rs[c][d] = Wo[d][c]
#pragma unroll
      for (int k = 0; k < 32; ++k) {
        int idx = t + k * 256, cc = idx & 63, col = idx >> 6;
        Rs[cc][col] = Wo[(dc * 128 + col) * 64 + cc];
      }
    }
    __syncthreads();
#pragma unroll 4
    for (int d = 0; d < 128; ++d) {
      float rv = Rs[b][d];
      acc0 = fmaf(Ls[2 * ag][d], rv, acc0);
      acc1 = fmaf(Ls[2 * ag + 1][d], rv, acc1);
    }
  }
  float* o = ws + m * 4096;
  const int r0 = a0 + 2 * ag, r1 = r0 + 1;
  o[(r0 >> 2) * 256 + b * 4 + (r0 & 3)] = acc0;
  o[(r1 >> 2) * 256 + b * 4 + (r1 & 3)] = acc1;
}

// ---------------- K1b: vectors, scalars, positional table ----------------
__global__ __launch_bounds__(512) void k1_vec(
    const float* __restrict__ Wq, const float* __restrict__ bq,
    const float* __restrict__ Wk, const float* __restrict__ bk,
    const float* __restrict__ Wv, const float* __restrict__ bv,
    const float* __restrict__ Wo, float* __restrict__ ws)
{
  const int t = threadIdx.x, w = t >> 6, lane = t & 63;
  // five W@b vectors: v0=Wq@bk v1=Wk@bq v2=Wq@bq v3=Wk@bk v4=Wv@bv
  for (int idx = w; idx < 320; idx += 8) {
    const int v = idx >> 6, a = idx & 63;
    const float* L = (v == 0 || v == 2) ? Wq : (v == 1 || v == 3) ? Wk : Wv;
    const float* r = (v == 0 || v == 3) ? bk : (v == 1 || v == 2) ? bq : bv;
    float p = 0.f;
#pragma unroll
    for (int d = 0; d < 8; ++d) p = fmaf(L[a * 512 + lane + d * 64], r[lane + d * 64], p);
#pragma unroll
    for (int dd = 1; dd < 64; dd <<= 1) p += __shfl_xor(p, dd);
    if (lane == 0) ws[WS_PQ + v * 64 + a] = p;
  }
  if (w == 0) {          // rvo[c] = sum_d bv[d]*Wo[d][c]
    float p = 0.f;
    for (int d = 0; d < 512; ++d) p = fmaf(bv[d], Wo[d * 64 + lane], p);
    ws[WS_RVO + lane] = p;
  } else if (w == 1) {   // scalars
#pragma unroll
    for (int s = 0; s < 4; ++s) {
      const float* u  = (s <= 1) ? bq : (s == 2) ? bk : bv;
      const float* vv = (s == 0 || s == 2) ? bk : (s == 1) ? bq : bv;
      float p = 0.f;
#pragma unroll
      for (int d = 0; d < 8; ++d) p = fmaf(u[lane + d * 64], vv[lane + d * 64], p);
#pragma unroll
      for (int dd = 1; dd < 64; dd <<= 1) p += __shfl_xor(p, dd);
      if (lane == 0) ws[WS_SC + s] = p;
    }
  }
  // positional encoding: pe[f][2m]=sin(f*div_m), pe[f][2m+1]=cos(f*div_m)
  for (int idx = t; idx < 1024; idx += 512) {
    int f = idx >> 6, ch = idx & 63;
    float div = __expf(-(float)(ch & ~1) * 0.14391156510303f);  // ln(1e4)/64
    float arg = (float)f * div;
    ws[WS_PE + idx] = (ch & 1) ? cosf(arg) : sinf(arg);
  }
}

// ---------------- K2: main fused kernel, 1 wave = 1 pixel ----------------
__global__ __launch_bounds__(512) void k2_main(
    const float* __restrict__ x, const float* __restrict__ ws,
    const float* __restrict__ bo_g, float* __restrict__ out)
{
  __shared__ float xs[8 * XSTRIDE];            // per-pixel [16][XPAD] fp32 (+pe), later final out
  __shared__ unsigned short scr[8 * 16 * SPAD];// per-pixel bf16 scratch: T~ rows, then W rows
  __shared__ float nrm[8 * 48];                // inv_nq[16], inv_nk[16], inv_nv[16] per pixel

  const int t = threadIdx.x;
  const int w = t >> 6, lane = t & 63;
  const int n0 = blockIdx.x * 8;
  const int bb = n0 >> 12, rem = n0 & 4095;
  const int pbase = (rem >> 6) * 64 + (rem & 63);

  {  // cooperative coalesced stage: xs = x + pe
    const int px = t & 7, cc = (t >> 3) & 63;
    const float* xb = x + (size_t)(bb * 16 * 64) * 4096 + pbase + px;
    float* xd = xs + px * XSTRIDE;
#pragma unroll
    for (int f = 0; f < 16; ++f)
      xd[f * XPAD + cc] = xb[(f * 64 + cc) * 4096] + ws[WS_PE + f * 64 + cc];
  }
  const float uq2 = 2.f * ws[WS_UQ + lane], uk2 = 2.f * ws[WS_UK + lane], uv2 = 2.f * ws[WS_UV + lane];
  const float pqv = ws[WS_PQ + lane], pkv = ws[WS_PK + lane];
  const float rvov = ws[WS_RVO + lane], bov = bo_g[lane];
  const float c0 = ws[WS_SC], sq = ws[WS_SC + 1], sk = ws[WS_SC + 2], sv = ws[WS_SC + 3];
  __syncthreads();

  float* xsW = xs + w * XSTRIDE;
  unsigned short* scrW = scr + w * 16 * SPAD;
  float* nrmW = nrm + w * 48;
  const float* At = ws + 0     + lane * 4;
  const float* Qt = ws + 4096  + lane * 4;
  const float* Kt = ws + 8192  + lane * 4;
  const float* Vt = ws + 12288 + lane * 4;
  const float* Mt = ws + 16384 + lane * 4;

  // ---- pass A: T~ = xs@A + pk (lane=col), Zq = xs@Gq, Zk = xs@Gk
  float T[16], Zq[16], Zk[16];
#pragma unroll
  for (int i = 0; i < 16; ++i) { T[i] = pkv; Zq[i] = 0.f; Zk[i] = 0.f; }
  for (int a = 0; a < 64; a += 4) {
    const int aq = (a >> 2) * 256;
    const float4 av = *(const float4*)(At + aq);
    const float4 qv = *(const float4*)(Qt + aq);
    const float4 kv = *(const float4*)(Kt + aq);
#pragma unroll
    for (int i = 0; i < 16; ++i) {
      const float4 xq = *(const float4*)(xsW + i * XPAD + a);  // wave-uniform broadcast
      T[i]  = fmaf(xq.x, av.x, T[i]);  T[i]  = fmaf(xq.y, av.y, T[i]);
      T[i]  = fmaf(xq.z, av.z, T[i]);  T[i]  = fmaf(xq.w, av.w, T[i]);
      Zq[i] = fmaf(xq.x, qv.x, Zq[i]); Zq[i] = fmaf(xq.y, qv.y, Zq[i]);
      Zq[i] = fmaf(xq.z, qv.z, Zq[i]); Zq[i] = fmaf(xq.w, qv.w, Zq[i]);
      Zk[i] = fmaf(xq.x, kv.x, Zk[i]); Zk[i] = fmaf(xq.y, kv.y, Zk[i]);
      Zk[i] = fmaf(xq.z, kv.z, Zk[i]); Zk[i] = fmaf(xq.w, kv.w, Zk[i]);
    }
  }
#pragma unroll
  for (int i = 0; i < 16; ++i) scrW[i * SPAD + lane] = f2bf(T[i]);  // stage T~ (bf16)

  // ---- pass B: Zv = xs@Gv, Yv = xs@Mvo + rvo
  float Zv[16], Yv[16];
#pragma unroll
  for (int i = 0; i < 16; ++i) { Zv[i] = 0.f; Yv[i] = rvov; }
  for (int a = 0; a < 64; a += 4) {
    const int aq = (a >> 2) * 256;
    const float4 vv = *(const float4*)(Vt + aq);
    const float4 mv = *(const float4*)(Mt + aq);
#pragma unroll
    for (int i = 0; i < 16; ++i) {
      const float4 xq = *(const float4*)(xsW + i * XPAD + a);
      Zv[i] = fmaf(xq.x, vv.x, Zv[i]); Zv[i] = fmaf(xq.y, vv.y, Zv[i]);
      Zv[i] = fmaf(xq.z, vv.z, Zv[i]); Zv[i] = fmaf(xq.w, vv.w, Zv[i]);
      Yv[i] = fmaf(xq.x, mv.x, Yv[i]); Yv[i] = fmaf(xq.y, mv.y, Yv[i]);
      Yv[i] = fmaf(xq.z, mv.z, Yv[i]); Yv[i] = fmaf(xq.w, mv.w, Yv[i]);
    }
  }

  // ---- norms (|Q|,|K|,|V| via quadratic forms) + pq_row
  float pqc[16];
#pragma unroll
  for (int i = 0; i < 16; ++i) {
    const float xv = xsW[i * XPAD + lane];
    float v0 = (Zq[i] + uq2) * xv;
    float v1 = (Zk[i] + uk2) * xv;
    float v2 = (Zv[i] + uv2) * xv;
    float v3 = pqv * xv;
#pragma unroll
    for (int dd = 1; dd < 64; dd <<= 1) {
      v0 += __shfl_xor(v0, dd); v1 += __shfl_xor(v1, dd);
      v2 += __shfl_xor(v2, dd); v3 += __shfl_xor(v3, dd);
    }
    pqc[i] = v3 + c0;
    if (lane == 0) {
      nrmW[i]      = 1.f / fmaxf(sqrtf(v0 + sq), 1e-12f);
      nrmW[16 + i] = 1.f / fmaxf(sqrtf(v1 + sk), 1e-12f);
      nrmW[32 + i] = 1.f / fmaxf(sqrtf(v2 + sv), 1e-12f);
    }
  }

  // ---- S[i][j] = T~_i . xs_j + pqc[i], lane=(g,jj), a-chunked + cross-g reduce
  const int g = lane >> 4, jj = lane & 15;
  float s[16];
#pragma unroll
  for (int i = 0; i < 16; ++i) {
    float acc = 0.f;
#pragma unroll
    for (int h = 0; h < 2; ++h) {
      const int a0i = g * 16 + h * 8;
      const uint4 tq = ld_su4(scrW + i * SPAD + a0i);
      const float4 x0 = *(const float4*)(xsW + jj * XPAD + a0i);
      const float4 x1 = *(const float4*)(xsW + jj * XPAD + a0i + 4);
      acc = fmaf(bfl(tq.x), x0.x, acc); acc = fmaf(bfh(tq.x), x0.y, acc);
      acc = fmaf(bfl(tq.y), x0.z, acc); acc = fmaf(bfh(tq.y), x0.w, acc);
      acc = fmaf(bfl(tq.z), x1.x, acc); acc = fmaf(bfh(tq.z), x1.y, acc);
      acc = fmaf(bfl(tq.w), x1.z, acc); acc = fmaf(bfh(tq.w), x1.w, acc);
    }
    acc += __shfl_xor(acc, 16);
    acc += __shfl_xor(acc, 32);
    s[i] = acc + pqc[i];
  }

  // ---- softmax over j (16-lane groups), fold 1/|V_j| -> W rows into scr
  {
    const float ink = nrmW[16 + jj];
    const float ivv = nrmW[32 + jj];
#pragma unroll
    for (int i = 0; i < 16; ++i) {
      const float sc = s[i] * nrmW[i] * ink;
      float mx = sc;
#pragma unroll
      for (int dd = 1; dd < 16; dd <<= 1) mx = fmaxf(mx, __shfl_xor(mx, dd));
      const float e = __expf(sc - mx);
      float sum = e;
#pragma unroll
      for (int dd = 1; dd < 16; dd <<= 1) sum += __shfl_xor(sum, dd);
      const float p = e / sum;
      if (g == 0) scrW[i * SPAD + jj] = f2bf(p * ivv);
    }
  }

  // ---- final[i][c] = bo + resid + sum_j W[i][j]*Yv[j]; stage fp32 back into xs
#pragma unroll
  for (int i = 0; i < 16; ++i) {
    float acc = bov + xsW[i * XPAD + lane];
    const uint4 qa = ld_su4(scrW + i * SPAD);
    const uint4 qb = ld_su4(scrW + i * SPAD + 8);
    acc = fmaf(bfl(qa.x), Yv[0], acc);  acc = fmaf(bfh(qa.x), Yv[1], acc);
    acc = fmaf(bfl(qa.y), Yv[2], acc);  acc = fmaf(bfh(qa.y), Yv[3], acc);
    acc = fmaf(bfl(qa.z), Yv[4], acc);  acc = fmaf(bfh(qa.z), Yv[5], acc);
    acc = fmaf(bfl(qa.w), Yv[6], acc);  acc = fmaf(bfh(qa.w), Yv[7], acc);
    acc = fmaf(bfl(qb.x), Yv[8], acc);  acc = fmaf(bfh(qb.x), Yv[9], acc);
    acc = fmaf(bfl(qb.y), Yv[10], acc); acc = fmaf(bfh(qb.y), Yv[11], acc);
    acc = fmaf(bfl(qb.z), Yv[12], acc); acc = fmaf(bfh(qb.z), Yv[13], acc);
    acc = fmaf(bfl(qb.w), Yv[14], acc); acc = fmaf(bfh(qb.w), Yv[15], acc);
    xsW[i * XPAD + lane] = acc;
  }

  __syncthreads();
  {  // coalesced flush
    const int px = t & 7, cc = (t >> 3) & 63;
    float* ob = out + (size_t)(bb * 16 * 64) * 4096 + pbase + px;
    const float* xsrc = xs + px * XSTRIDE;
#pragma unroll
    for (int f = 0; f < 16; ++f)
      ob[(f * 64 + cc) * 4096] = xsrc[f * XPAD + cc];
  }
}

extern "C" void kernel_launch(void* const* d_in, const int* in_sizes, int n_in,
                              void* d_out, int out_size, void* d_ws, size_t ws_size,
                              hipStream_t stream) {
  const float* x  = (const float*)d_in[0];
  const float* Wq = (const float*)d_in[1];
  const float* bq = (const float*)d_in[2];
  const float* Wk = (const float*)d_in[3];
  const float* bk = (const float*)d_in[4];
  const float* Wv = (const float*)d_in[5];
  const float* bv = (const float*)d_in[6];
  const float* Wo = (const float*)d_in[7];
  const float* bo = (const float*)d_in[8];
  float* out = (float*)d_out;
  float* ws  = (float*)d_ws;
  (void)in_sizes; (void)n_in; (void)out_size; (void)ws_size;

  k1_mats<<<40, 256, 0, stream>>>(Wq, Wk, Wv, Wo, ws);
  k1_vec<<<1, 512, 0, stream>>>(Wq, bq, Wk, bk, Wv, bv, Wo, ws);
  k2_main<<<1024, 512, 0, stream>>>(x, ws, bo, out);
}

// Round 2
// 161.113 us; speedup vs baseline: 1.8663x; 1.8663x over previous
//
#include <hip/hip_runtime.h>

typedef __attribute__((ext_vector_type(8))) short short8v;
typedef __attribute__((ext_vector_type(4))) float f32x4;

// ---------------- workspace layout ----------------
// ws[0 .. 10239] (floats) = bf16 fragment table for 5 matrices:
//   shorts idx = ((m*2+kt)*4+ct)*512 + lane*8 + jj
//   holds M_m[k = kt*32 + sigma(lane,jj)][c = ct*16 + (lane&15)]
// m: 0=A_qk(WqWk^T) 1=G_q(WqWq^T) 2=G_k 3=G_v 4=M_vo(Wv@Wo)
#define WS_PQ  20480   // Wq@bk [64]
#define WS_PK  20544   // Wk@bq [64]
#define WS_UQ  20608   // Wq@bq
#define WS_UK  20672   // Wk@bk
#define WS_UV  20736   // Wv@bv
#define WS_RVO 20800   // bv@Wo [64]
#define WS_SC  20864   // c0=bq.bk, |bq|^2, |bk|^2, |bv|^2
#define WS_PE  20992   // pe[16][64]

#define RPX    4640    // per-pixel LDS region bytes (290*16, de-aliased vs 128)
#define PT_OFF 2064    // P-tilde A-frags (32 lanes * 16B)
#define YT_OFF 2576    // Yv B-frags (4 ct * 32 lanes * 16B)
#define NRM_OFF (8*RPX)

__device__ __forceinline__ unsigned short f2bf(float f) {
  unsigned u = __float_as_uint(f);
  u += 0x7fffu + ((u >> 16) & 1u);          // RNE
  return (unsigned short)(u >> 16);
}
__device__ __forceinline__ float bf2f(unsigned short h) {
  return __uint_as_float(((unsigned)h) << 16);
}
__device__ __forceinline__ f32x4 mfma16(short8v a, short8v b, f32x4 c) {
  return __builtin_amdgcn_mfma_f32_16x16x32_bf16(a, b, c, 0, 0, 0);
}

// ---------------- K1: matrices (bf16 frags) + vectors + scalars + pe ----------------
__global__ __launch_bounds__(256) void k1(
    const float* __restrict__ Wq, const float* __restrict__ bq,
    const float* __restrict__ Wk, const float* __restrict__ bk,
    const float* __restrict__ Wv, const float* __restrict__ bv,
    const float* __restrict__ Wo, float* __restrict__ ws)
{
  __shared__ float Ls[8][129];
  __shared__ float Rs[64][129];
  const int bid = blockIdx.x;
  const int t = threadIdx.x;

  if (bid < 40) {  // five 64x64 matrices -> bf16 B-fragment table
    const int m  = bid >> 3;
    const int a0 = (bid & 7) * 8;
    const int b  = t & 63, ag = t >> 6;
    const float* L = (m <= 1) ? Wq : (m == 2) ? Wk : Wv;
    const float* R = (m == 0 || m == 2) ? Wk : (m == 1) ? Wq : Wv;
    float acc0 = 0.f, acc1 = 0.f;
    for (int dc = 0; dc < 4; ++dc) {
      __syncthreads();
#pragma unroll
      for (int k = 0; k < 4; ++k) {
        int idx = t + k * 256, row = idx >> 7, col = idx & 127;
        Ls[row][col] = L[(a0 + row) * 512 + dc * 128 + col];
      }
      if (m < 4) {
#pragma unroll
        for (int k = 0; k < 32; ++k) {
          int idx = t + k * 256, row = idx >> 7, col = idx & 127;
          Rs[row][col] = R[row * 512 + dc * 128 + col];
        }
      } else {
#pragma unroll
        for (int k = 0; k < 32; ++k) {
          int idx = t + k * 256, cc = idx & 63, col = idx >> 6;
          Rs[cc][col] = Wo[(dc * 128 + col) * 64 + cc];
        }
      }
      __syncthreads();
#pragma unroll 4
      for (int d = 0; d < 128; ++d) {
        float rv = Rs[b][d];
        acc0 = fmaf(Ls[2 * ag][d], rv, acc0);
        acc1 = fmaf(Ls[2 * ag + 1][d], rv, acc1);
      }
    }
    unsigned short* wsu = (unsigned short*)ws;
    const int r0 = a0 + 2 * ag;
#pragma unroll
    for (int e = 0; e < 2; ++e) {
      const int a = r0 + e;
      const float v = e ? acc1 : acc0;
      const int kt = a >> 5, lane2 = ((a >> 3) & 3) * 16 + (b & 15);
      const int jj = a & 7, ct = b >> 4;
      wsu[((m * 2 + kt) * 4 + ct) * 512 + lane2 * 8 + jj] = f2bf(v);
    }
    return;
  }

  if (bid < 46) {  // six 64-vectors, one per block, wave-parallel
    const int v = bid - 40;
    const int wv = t >> 6, lane = t & 63;
    const float* L  = (v == 0 || v == 2) ? Wq : (v == 1 || v == 3) ? Wk : Wv;
    const float* rv = (v == 0 || v == 3) ? bk : (v == 1 || v == 2) ? bq : bv;
    const int dst = (v == 0) ? WS_PQ : (v == 1) ? WS_PK : (v == 2) ? WS_UQ
                  : (v == 3) ? WS_UK : (v == 4) ? WS_UV : WS_RVO;
    for (int a = wv; a < 64; a += 4) {
      float p = 0.f;
      if (v < 5) {
#pragma unroll
        for (int dd = 0; dd < 8; ++dd)
          p = fmaf(L[a * 512 + lane + dd * 64], rv[lane + dd * 64], p);
      } else {  // rvo[a] = sum_d bv[d]*Wo[d][a]
#pragma unroll
        for (int dd = 0; dd < 8; ++dd)
          p = fmaf(bv[lane + dd * 64], Wo[(lane + dd * 64) * 64 + a], p);
      }
#pragma unroll
      for (int dd = 1; dd < 64; dd <<= 1) p += __shfl_xor(p, dd);
      if (lane == 0) ws[dst + a] = p;
    }
    return;
  }

  // bid == 46: scalars + positional table
  if (t < 64) {
    const int lane = t;
#pragma unroll
    for (int s = 0; s < 4; ++s) {
      const float* u  = (s <= 1) ? bq : (s == 2) ? bk : bv;
      const float* vv = (s == 0 || s == 2) ? bk : (s == 1) ? bq : bv;
      float p = 0.f;
#pragma unroll
      for (int dd = 0; dd < 8; ++dd) p = fmaf(u[lane + dd * 64], vv[lane + dd * 64], p);
#pragma unroll
      for (int dd = 1; dd < 64; dd <<= 1) p += __shfl_xor(p, dd);
      if (lane == 0) ws[WS_SC + s] = p;
    }
  }
  for (int idx = t; idx < 1024; idx += 256) {
    int f = idx >> 6, ch = idx & 63;
    float div = __expf(-(float)(ch & ~1) * 0.14391156510303f);  // ln(1e4)/64
    float arg = (float)f * div;
    ws[WS_PE + idx] = (ch & 1) ? cosf(arg) : sinf(arg);
  }
}

// load 8 B-frags of matrix MM and accumulate 2 MFMAs into each of 4 col-tiles
template<int MM>
__device__ __forceinline__ void product5(const unsigned short* wsu, int lane,
                                         short8v xa0, short8v xa1, f32x4 (&acc)[4]) {
  const short8v b00 = *(const short8v*)(wsu + ((MM * 2 + 0) * 4 + 0) * 512 + lane * 8);
  const short8v b01 = *(const short8v*)(wsu + ((MM * 2 + 0) * 4 + 1) * 512 + lane * 8);
  const short8v b02 = *(const short8v*)(wsu + ((MM * 2 + 0) * 4 + 2) * 512 + lane * 8);
  const short8v b03 = *(const short8v*)(wsu + ((MM * 2 + 0) * 4 + 3) * 512 + lane * 8);
  const short8v b10 = *(const short8v*)(wsu + ((MM * 2 + 1) * 4 + 0) * 512 + lane * 8);
  const short8v b11 = *(const short8v*)(wsu + ((MM * 2 + 1) * 4 + 1) * 512 + lane * 8);
  const short8v b12 = *(const short8v*)(wsu + ((MM * 2 + 1) * 4 + 2) * 512 + lane * 8);
  const short8v b13 = *(const short8v*)(wsu + ((MM * 2 + 1) * 4 + 3) * 512 + lane * 8);
  acc[0] = mfma16(xa0, b00, acc[0]);
  acc[1] = mfma16(xa0, b01, acc[1]);
  acc[2] = mfma16(xa0, b02, acc[2]);
  acc[3] = mfma16(xa0, b03, acc[3]);
  acc[0] = mfma16(xa1, b10, acc[0]);
  acc[1] = mfma16(xa1, b11, acc[1]);
  acc[2] = mfma16(xa1, b12, acc[2]);
  acc[3] = mfma16(xa1, b13, acc[3]);
}

// ---------------- K2: fused main kernel, 1 wave = 1 pixel ----------------
__global__ __launch_bounds__(512, 4) void k2_main(
    const float* __restrict__ x, const float* __restrict__ ws,
    const float* __restrict__ bo_g, float* __restrict__ out)
{
  __shared__ uint4 lds4[2384];   // 8*RPX + 8*32*4 = 38144 B
  char* lds = (char*)lds4;

  const int t = threadIdx.x;
  const int bid = blockIdx.x;
  // XCD-pair swizzle: blocks sharing a 64B input line land on the same XCD
  const int pb = (bid & ~15) | (((bid & 7) << 1) | ((bid >> 3) & 1));
  const int n0 = pb * 8;
  const size_t gbase = (size_t)(n0 >> 12) * 4194304 + (n0 & 4095);
  const unsigned short* wsu = (const unsigned short*)ws;

  {  // cooperative stage: xs = x + pe -> bf16 A-fragment-packed LDS
    const int px = t & 7, cc = t >> 3;
    const float* xb = x + gbase + px;
    char* wb = lds + px * RPX + (cc >> 5) * 1024 + (((cc >> 3) & 3) * 16) * 16 + (cc & 7) * 2;
#pragma unroll
    for (int f = 0; f < 16; ++f) {
      float v = xb[(size_t)(f * 64 + cc) * 4096] + ws[WS_PE + f * 64 + cc];
      *(unsigned short*)(wb + f * 16) = f2bf(v);
    }
  }
  __syncthreads();

  const int w = t >> 6, lane = t & 63, g = lane >> 4, lc = lane & 15;
  char* P = lds + w * RPX;
  float* nrmW = (float*)(lds + NRM_OFF) + w * 32;

  // xs A-fragments (also reused as B-operand for the score MFMA)
  const short8v xa0 = *(const short8v*)(P + lane * 16);
  const short8v xa1 = *(const short8v*)(P + 1024 + lane * 16);

  // per-lane xs values at this lane's D-layout positions (i=4g+r, c=16ct+lc)
  float xr[4][4];
#pragma unroll
  for (int r = 0; r < 4; ++r)
#pragma unroll
    for (int ct = 0; ct < 4; ++ct) {
      const int c = 16 * ct + lc, i = 4 * g + r;
      xr[r][ct] = bf2f(*(const unsigned short*)(
          P + (c >> 5) * 1024 + (((c >> 3) & 3) * 16 + i) * 16 + (c & 7) * 2));
    }

  float uq2[4], uk2[4], uv2[4], pqv[4];
#pragma unroll
  for (int ct = 0; ct < 4; ++ct) {
    const int c = 16 * ct + lc;
    uq2[ct] = 2.f * ws[WS_UQ + c];
    uk2[ct] = 2.f * ws[WS_UK + c];
    uv2[ct] = 2.f * ws[WS_UV + c];
    pqv[ct] = ws[WS_PQ + c];
  }
  const float c0 = ws[WS_SC], sq = ws[WS_SC + 1], sk2 = ws[WS_SC + 2], sv2 = ws[WS_SC + 3];

  const f32x4 z4 = {0.f, 0.f, 0.f, 0.f};
  f32x4 acc[4];
  float nqp[4], nkp[4], nvp[4], pqp[4];

  // ---- Zq = xs@G_q -> |Q| partials
#pragma unroll
  for (int ct = 0; ct < 4; ++ct) acc[ct] = z4;
  product5<1>(wsu, lane, xa0, xa1, acc);
#pragma unroll
  for (int r = 0; r < 4; ++r) {
    float s2 = 0.f;
#pragma unroll
    for (int ct = 0; ct < 4; ++ct) s2 = fmaf(acc[ct][r] + uq2[ct], xr[r][ct], s2);
    nqp[r] = s2;
  }
  // ---- Zk
#pragma unroll
  for (int ct = 0; ct < 4; ++ct) acc[ct] = z4;
  product5<2>(wsu, lane, xa0, xa1, acc);
#pragma unroll
  for (int r = 0; r < 4; ++r) {
    float s2 = 0.f;
#pragma unroll
    for (int ct = 0; ct < 4; ++ct) s2 = fmaf(acc[ct][r] + uk2[ct], xr[r][ct], s2);
    nkp[r] = s2;
  }
  // ---- Zv
#pragma unroll
  for (int ct = 0; ct < 4; ++ct) acc[ct] = z4;
  product5<3>(wsu, lane, xa0, xa1, acc);
#pragma unroll
  for (int r = 0; r < 4; ++r) {
    float s2 = 0.f, p2 = 0.f;
#pragma unroll
    for (int ct = 0; ct < 4; ++ct) {
      s2 = fmaf(acc[ct][r] + uv2[ct], xr[r][ct], s2);
      p2 = fmaf(pqv[ct], xr[r][ct], p2);
    }
    nvp[r] = s2;
    pqp[r] = p2;
  }

  // ---- reduce over the 16-lane column group; norms + row bias
  float invq[4], pqc[4];
#pragma unroll
  for (int r = 0; r < 4; ++r) {
    float a0 = nqp[r], a1 = nkp[r], a2 = nvp[r], a3 = pqp[r];
#pragma unroll
    for (int dd = 1; dd < 16; dd <<= 1) {
      a0 += __shfl_xor(a0, dd); a1 += __shfl_xor(a1, dd);
      a2 += __shfl_xor(a2, dd); a3 += __shfl_xor(a3, dd);
    }
    invq[r] = rsqrtf(a0 + sq);
    pqc[r] = a3 + c0;
    if (lc == 0) {
      nrmW[4 * g + r]      = rsqrtf(a1 + sk2);
      nrmW[16 + 4 * g + r] = rsqrtf(a2 + sv2);
    }
  }

  // ---- T~ = xs@A_qk + pk; restage as bf16 A-frags (overlays xsb, now dead)
  float pkv[4];
#pragma unroll
  for (int ct = 0; ct < 4; ++ct) pkv[ct] = ws[WS_PK + 16 * ct + lc];
#pragma unroll
  for (int ct = 0; ct < 4; ++ct) { f32x4 v = {pkv[ct], pkv[ct], pkv[ct], pkv[ct]}; acc[ct] = v; }
  product5<0>(wsu, lane, xa0, xa1, acc);
#pragma unroll
  for (int r = 0; r < 4; ++r)
#pragma unroll
    for (int ct = 0; ct < 4; ++ct) {
      const int c = 16 * ct + lc, i = 4 * g + r;
      *(unsigned short*)(P + (c >> 5) * 1024 + (((c >> 3) & 3) * 16 + i) * 16 + (c & 7) * 2)
          = f2bf(acc[ct][r]);
    }

  // ---- scores: S = T~ @ xs^T + pqc (B-frag of xs^T == A-frag of xs)
  const short8v ta0 = *(const short8v*)(P + lane * 16);
  const short8v ta1 = *(const short8v*)(P + 1024 + lane * 16);
  f32x4 sv = {pqc[0], pqc[1], pqc[2], pqc[3]};
  sv = mfma16(ta0, xa0, sv);
  sv = mfma16(ta1, xa1, sv);

  // ---- Yv = xs@M_vo + rvo (independent of softmax; overlaps MFMA pipe)
  float rvo[4];
#pragma unroll
  for (int ct = 0; ct < 4; ++ct) rvo[ct] = ws[WS_RVO + 16 * ct + lc];
#pragma unroll
  for (int ct = 0; ct < 4; ++ct) { f32x4 v = {rvo[ct], rvo[ct], rvo[ct], rvo[ct]}; acc[ct] = v; }
  product5<4>(wsu, lane, xa0, xa1, acc);

  // ---- softmax over j (=lc) per row r, fold 1/|V_j|; stage P A-frags
  const float ikj = nrmW[lc], ivj = nrmW[16 + lc];
  float sc0 = sv[0] * invq[0] * ikj;
  float sc1 = sv[1] * invq[1] * ikj;
  float sc2 = sv[2] * invq[2] * ikj;
  float sc3 = sv[3] * invq[3] * ikj;
  float m0 = sc0, m1 = sc1, m2 = sc2, m3 = sc3;
#pragma unroll
  for (int dd = 1; dd < 16; dd <<= 1) {
    m0 = fmaxf(m0, __shfl_xor(m0, dd)); m1 = fmaxf(m1, __shfl_xor(m1, dd));
    m2 = fmaxf(m2, __shfl_xor(m2, dd)); m3 = fmaxf(m3, __shfl_xor(m3, dd));
  }
  float e0 = __expf(sc0 - m0), e1 = __expf(sc1 - m1), e2 = __expf(sc2 - m2), e3 = __expf(sc3 - m3);
  float u0 = e0, u1 = e1, u2 = e2, u3 = e3;
#pragma unroll
  for (int dd = 1; dd < 16; dd <<= 1) {
    u0 += __shfl_xor(u0, dd); u1 += __shfl_xor(u1, dd);
    u2 += __shfl_xor(u2, dd); u3 += __shfl_xor(u3, dd);
  }
  const float w0 = e0 / u0 * ivj, w1 = e1 / u1 * ivj, w2 = e2 / u2 * ivj, w3 = e3 / u3 * ivj;
  {
    char* pt = P + PT_OFF + ((lc >> 3) * 16 + 4 * g) * 16 + (lc & 7) * 2;
    *(unsigned short*)(pt)      = f2bf(w0);
    *(unsigned short*)(pt + 16) = f2bf(w1);
    *(unsigned short*)(pt + 32) = f2bf(w2);
    *(unsigned short*)(pt + 48) = f2bf(w3);
  }

  // ---- stage Yv as bf16 B-frags (k = j < 16 -> lanes 0..31 only)
#pragma unroll
  for (int r = 0; r < 4; ++r) {
    const int j = 4 * g + r;
    char* yt = P + YT_OFF + ((j >> 3) * 16 + lc) * 16 + (j & 7) * 2;
#pragma unroll
    for (int ct = 0; ct < 4; ++ct)
      *(unsigned short*)(yt + ct * 512) = f2bf(acc[ct][r]);
  }

  // ---- PV + bias + residual (acc init = bo + resid), D-layout output
  float bov[4];
#pragma unroll
  for (int ct = 0; ct < 4; ++ct) bov[ct] = bo_g[16 * ct + lc];
  short8v pa = {0, 0, 0, 0, 0, 0, 0, 0};
  if (lane < 32) pa = *(const short8v*)(P + PT_OFF + lane * 16);
  f32x4 o[4];
#pragma unroll
  for (int ct = 0; ct < 4; ++ct) {
    f32x4 v = {bov[ct] + xr[0][ct], bov[ct] + xr[1][ct], bov[ct] + xr[2][ct], bov[ct] + xr[3][ct]};
    o[ct] = v;
  }
#pragma unroll
  for (int ct = 0; ct < 4; ++ct) {
    short8v yb = {0, 0, 0, 0, 0, 0, 0, 0};
    if (lane < 32) yb = *(const short8v*)(P + YT_OFF + ct * 512 + lane * 16);
    o[ct] = mfma16(pa, yb, o[ct]);
  }

  // ---- stage final fp32 [16][68] (overlays frag buffers, all dead)
#pragma unroll
  for (int ct = 0; ct < 4; ++ct)
#pragma unroll
    for (int r = 0; r < 4; ++r)
      *(float*)(P + (4 * g + r) * 272 + (16 * ct + lc) * 4) = o[ct][r];

  __syncthreads();
  {  // coalesced flush
    const int px = t & 7, cc = t >> 3;
    float* ob = out + gbase + px;
    const char* rb = lds + px * RPX;
#pragma unroll
    for (int f = 0; f < 16; ++f)
      ob[(size_t)(f * 64 + cc) * 4096] = *(const float*)(rb + f * 272 + cc * 4);
  }
}

extern "C" void kernel_launch(void* const* d_in, const int* in_sizes, int n_in,
                              void* d_out, int out_size, void* d_ws, size_t ws_size,
                              hipStream_t stream) {
  const float* x  = (const float*)d_in[0];
  const float* Wq = (const float*)d_in[1];
  const float* bq = (const float*)d_in[2];
  const float* Wk = (const float*)d_in[3];
  const float* bk = (const float*)d_in[4];
  const float* Wv = (const float*)d_in[5];
  const float* bv = (const float*)d_in[6];
  const float* Wo = (const float*)d_in[7];
  const float* bo = (const float*)d_in[8];
  float* out = (float*)d_out;
  float* ws  = (float*)d_ws;
  (void)in_sizes; (void)n_in; (void)out_size; (void)ws_size;

  k1<<<47, 256, 0, stream>>>(Wq, bq, Wk, bk, Wv, bv, Wo, ws);
  k2_main<<<1024, 512, 0, stream>>>(x, ws, bo, out);
}

// Round 3
// 138.267 us; speedup vs baseline: 2.1747x; 1.1652x over previous
//
#include <hip/hip_runtime.h>

typedef __attribute__((ext_vector_type(8))) short short8v;
typedef __attribute__((ext_vector_type(4))) float f32x4;

// ---------------- workspace layout ----------------
// ws[0 .. 10239] (floats) = bf16 fragment table for 5 matrices:
//   shorts idx = ((m*2+kt)*4+ct)*512 + lane*8 + jj
//   holds M_m[k = kt*32 + sigma(lane,jj)][c = ct*16 + (lane&15)]
// m: 0=A_qk(WqWk^T) 1=G_q(WqWq^T) 2=G_k 3=G_v 4=M_vo(Wv@Wo)
#define WS_PQ  20480   // Wq@bk [64]
#define WS_PK  20544   // Wk@bq [64]
#define WS_UQ  20608   // Wq@bq
#define WS_UK  20672   // Wk@bk
#define WS_UV  20736   // Wv@bv
#define WS_RVO 20800   // bv@Wo [64]
#define WS_SC  20864   // c0=bq.bk, |bq|^2, |bk|^2, |bv|^2
#define WS_PE  20992   // pe[16][64]

#define RPX    4640    // per-pixel LDS region bytes (290*16, de-aliased vs 128)
#define PT_OFF 2064    // P-tilde A-frags (32 lanes * 16B)
#define YT_OFF 2576    // Yv B-frags (4 ct * 32 lanes * 16B)
#define NRM_OFF (8*RPX)

__device__ __forceinline__ unsigned short f2bf(float f) {
  unsigned u = __float_as_uint(f);
  u += 0x7fffu + ((u >> 16) & 1u);          // RNE
  return (unsigned short)(u >> 16);
}
__device__ __forceinline__ float bf2f(unsigned short h) {
  return __uint_as_float(((unsigned)h) << 16);
}
__device__ __forceinline__ f32x4 mfma16(short8v a, short8v b, f32x4 c) {
  return __builtin_amdgcn_mfma_f32_16x16x32_bf16(a, b, c, 0, 0, 0);
}

// ---------------- K1: fully wave-parallel precompute ----------------
// wave-jobs: 0..319  = matrix rows (m = wid>>6, a = wid&63), lane = output col
//            320..324 = vectors v0..v4 (lane = output row)
//            325      = rvo (lane = output col, Wo coalesced)
//            326      = 4 scalars (lane-parallel dot + reduce)
//            327      = positional-encoding table
__global__ __launch_bounds__(256) void k1(
    const float* __restrict__ Wq, const float* __restrict__ bq,
    const float* __restrict__ Wk, const float* __restrict__ bk,
    const float* __restrict__ Wv, const float* __restrict__ bv,
    const float* __restrict__ Wo, float* __restrict__ ws)
{
  const int lane = threadIdx.x & 63;
  const int wid  = (blockIdx.x << 2) | (threadIdx.x >> 6);
  unsigned short* wsu = (unsigned short*)ws;

  if (wid < 320) {  // M_m[a][c=lane] = dot over d=0..511
    const int m = wid >> 6, a = wid & 63;
    float a0 = 0.f, a1 = 0.f, a2 = 0.f, a3 = 0.f;
    if (m < 4) {
      const float* L = (m <= 1) ? Wq : (m == 2) ? Wk : Wv;
      const float* R = (m == 1) ? Wq : (m == 3) ? Wv : Wk;  // m0,m2 -> Wk
      const float* Lr = L + a * 512;
      const float* Rr = R + lane * 512;
#pragma unroll 4
      for (int d = 0; d < 512; d += 4) {
        const float4 l4 = *(const float4*)(Lr + d);
        const float4 r4 = *(const float4*)(Rr + d);
        a0 = fmaf(l4.x, r4.x, a0); a1 = fmaf(l4.y, r4.y, a1);
        a2 = fmaf(l4.z, r4.z, a2); a3 = fmaf(l4.w, r4.w, a3);
      }
    } else {        // M_vo[a][c] = sum_d Wv[a][d] * Wo[d][c], coalesced Wo
      const float* Lr = Wv + a * 512;
#pragma unroll 4
      for (int d = 0; d < 512; d += 4) {
        const float4 l4 = *(const float4*)(Lr + d);
        a0 = fmaf(l4.x, Wo[(d + 0) * 64 + lane], a0);
        a1 = fmaf(l4.y, Wo[(d + 1) * 64 + lane], a1);
        a2 = fmaf(l4.z, Wo[(d + 2) * 64 + lane], a2);
        a3 = fmaf(l4.w, Wo[(d + 3) * 64 + lane], a3);
      }
    }
    const float p = (a0 + a1) + (a2 + a3);
    const int c = lane;
    wsu[((m * 2 + (a >> 5)) * 4 + (c >> 4)) * 512
        + (((a >> 3) & 3) * 16 + (c & 15)) * 8 + (a & 7)] = f2bf(p);
    return;
  }

  if (wid < 325) {  // vectors: out[a=lane] = dot(L_row(a), r)
    const int v = wid - 320;
    const float* L = (v == 0 || v == 2) ? Wq : (v == 1 || v == 3) ? Wk : Wv;
    const float* r = (v == 0 || v == 3) ? bk : (v == 1 || v == 2) ? bq : bv;
    const int dst = (v == 0) ? WS_PQ : (v == 1) ? WS_PK : (v == 2) ? WS_UQ
                  : (v == 3) ? WS_UK : WS_UV;
    const float* Lr = L + lane * 512;
    float a0 = 0.f, a1 = 0.f, a2 = 0.f, a3 = 0.f;
#pragma unroll 4
    for (int d = 0; d < 512; d += 4) {
      const float4 l4 = *(const float4*)(Lr + d);
      const float4 r4 = *(const float4*)(r + d);
      a0 = fmaf(l4.x, r4.x, a0); a1 = fmaf(l4.y, r4.y, a1);
      a2 = fmaf(l4.z, r4.z, a2); a3 = fmaf(l4.w, r4.w, a3);
    }
    ws[dst + lane] = (a0 + a1) + (a2 + a3);
    return;
  }

  if (wid == 325) {  // rvo[c=lane] = sum_d bv[d] * Wo[d][c]
    float a0 = 0.f, a1 = 0.f, a2 = 0.f, a3 = 0.f;
#pragma unroll 4
    for (int d = 0; d < 512; d += 4) {
      const float4 b4 = *(const float4*)(bv + d);
      a0 = fmaf(b4.x, Wo[(d + 0) * 64 + lane], a0);
      a1 = fmaf(b4.y, Wo[(d + 1) * 64 + lane], a1);
      a2 = fmaf(b4.z, Wo[(d + 2) * 64 + lane], a2);
      a3 = fmaf(b4.w, Wo[(d + 3) * 64 + lane], a3);
    }
    ws[WS_RVO + lane] = (a0 + a1) + (a2 + a3);
    return;
  }

  if (wid == 326) {  // scalars: c0=bq.bk, |bq|^2, |bk|^2, |bv|^2
#pragma unroll
    for (int s = 0; s < 4; ++s) {
      const float* u  = (s <= 1) ? bq : (s == 2) ? bk : bv;
      const float* vv = (s == 0 || s == 2) ? bk : (s == 1) ? bq : bv;
      float p = 0.f;
#pragma unroll
      for (int dd = 0; dd < 8; ++dd) p = fmaf(u[lane + dd * 64], vv[lane + dd * 64], p);
#pragma unroll
      for (int dd = 1; dd < 64; dd <<= 1) p += __shfl_xor(p, dd);
      if (lane == 0) ws[WS_SC + s] = p;
    }
    return;
  }

  if (wid == 327) {  // positional encoding
    for (int idx = lane; idx < 1024; idx += 64) {
      int f = idx >> 6, ch = idx & 63;
      float div = __expf(-(float)(ch & ~1) * 0.14391156510303f);  // ln(1e4)/64
      float arg = (float)f * div;
      ws[WS_PE + idx] = (ch & 1) ? cosf(arg) : sinf(arg);
    }
  }
}

// load 8 B-frags of matrix MM and accumulate 2 MFMAs into each of 4 col-tiles
template<int MM>
__device__ __forceinline__ void product5(const unsigned short* wsu, int lane,
                                         short8v xa0, short8v xa1, f32x4 (&acc)[4]) {
  const short8v b00 = *(const short8v*)(wsu + ((MM * 2 + 0) * 4 + 0) * 512 + lane * 8);
  const short8v b01 = *(const short8v*)(wsu + ((MM * 2 + 0) * 4 + 1) * 512 + lane * 8);
  const short8v b02 = *(const short8v*)(wsu + ((MM * 2 + 0) * 4 + 2) * 512 + lane * 8);
  const short8v b03 = *(const short8v*)(wsu + ((MM * 2 + 0) * 4 + 3) * 512 + lane * 8);
  const short8v b10 = *(const short8v*)(wsu + ((MM * 2 + 1) * 4 + 0) * 512 + lane * 8);
  const short8v b11 = *(const short8v*)(wsu + ((MM * 2 + 1) * 4 + 1) * 512 + lane * 8);
  const short8v b12 = *(const short8v*)(wsu + ((MM * 2 + 1) * 4 + 2) * 512 + lane * 8);
  const short8v b13 = *(const short8v*)(wsu + ((MM * 2 + 1) * 4 + 3) * 512 + lane * 8);
  acc[0] = mfma16(xa0, b00, acc[0]);
  acc[1] = mfma16(xa0, b01, acc[1]);
  acc[2] = mfma16(xa0, b02, acc[2]);
  acc[3] = mfma16(xa0, b03, acc[3]);
  acc[0] = mfma16(xa1, b10, acc[0]);
  acc[1] = mfma16(xa1, b11, acc[1]);
  acc[2] = mfma16(xa1, b12, acc[2]);
  acc[3] = mfma16(xa1, b13, acc[3]);
}

// ---------------- K2: fused main kernel, 1 wave = 1 pixel ----------------
__global__ __launch_bounds__(512, 4) void k2_main(
    const float* __restrict__ x, const float* __restrict__ ws,
    const float* __restrict__ bo_g, float* __restrict__ out)
{
  __shared__ uint4 lds4[2384];   // 8*RPX + 8*32*4 = 38144 B
  char* lds = (char*)lds4;

  const int t = threadIdx.x;
  const int bid = blockIdx.x;
  // XCD-pair swizzle: blocks sharing a 64B input line land on the same XCD
  const int pb = (bid & ~15) | (((bid & 7) << 1) | ((bid >> 3) & 1));
  const int n0 = pb * 8;
  const size_t gbase = (size_t)(n0 >> 12) * 4194304 + (n0 & 4095);
  const unsigned short* wsu = (const unsigned short*)ws;

  {  // cooperative stage: xs = x + pe -> bf16 A-fragment-packed LDS
    const int px = t & 7, cc = t >> 3;
    const float* xb = x + gbase + px;
    char* wb = lds + px * RPX + (cc >> 5) * 1024 + (((cc >> 3) & 3) * 16) * 16 + (cc & 7) * 2;
#pragma unroll
    for (int f = 0; f < 16; ++f) {
      float v = xb[(size_t)(f * 64 + cc) * 4096] + ws[WS_PE + f * 64 + cc];
      *(unsigned short*)(wb + f * 16) = f2bf(v);
    }
  }
  __syncthreads();

  const int w = t >> 6, lane = t & 63, g = lane >> 4, lc = lane & 15;
  char* P = lds + w * RPX;
  float* nrmW = (float*)(lds + NRM_OFF) + w * 32;

  // xs A-fragments (also reused as B-operand for the score MFMA)
  const short8v xa0 = *(const short8v*)(P + lane * 16);
  const short8v xa1 = *(const short8v*)(P + 1024 + lane * 16);

  // per-lane xs values at this lane's D-layout positions (i=4g+r, c=16ct+lc)
  float xr[4][4];
#pragma unroll
  for (int r = 0; r < 4; ++r)
#pragma unroll
    for (int ct = 0; ct < 4; ++ct) {
      const int c = 16 * ct + lc, i = 4 * g + r;
      xr[r][ct] = bf2f(*(const unsigned short*)(
          P + (c >> 5) * 1024 + (((c >> 3) & 3) * 16 + i) * 16 + (c & 7) * 2));
    }

  float uq2[4], uk2[4], uv2[4], pqv[4];
#pragma unroll
  for (int ct = 0; ct < 4; ++ct) {
    const int c = 16 * ct + lc;
    uq2[ct] = 2.f * ws[WS_UQ + c];
    uk2[ct] = 2.f * ws[WS_UK + c];
    uv2[ct] = 2.f * ws[WS_UV + c];
    pqv[ct] = ws[WS_PQ + c];
  }
  const float c0 = ws[WS_SC], sq = ws[WS_SC + 1], sk2 = ws[WS_SC + 2], sv2 = ws[WS_SC + 3];

  const f32x4 z4 = {0.f, 0.f, 0.f, 0.f};
  f32x4 acc[4];
  float nqp[4], nkp[4], nvp[4], pqp[4];

  // ---- Zq = xs@G_q -> |Q| partials
#pragma unroll
  for (int ct = 0; ct < 4; ++ct) acc[ct] = z4;
  product5<1>(wsu, lane, xa0, xa1, acc);
#pragma unroll
  for (int r = 0; r < 4; ++r) {
    float s2 = 0.f;
#pragma unroll
    for (int ct = 0; ct < 4; ++ct) s2 = fmaf(acc[ct][r] + uq2[ct], xr[r][ct], s2);
    nqp[r] = s2;
  }
  // ---- Zk
#pragma unroll
  for (int ct = 0; ct < 4; ++ct) acc[ct] = z4;
  product5<2>(wsu, lane, xa0, xa1, acc);
#pragma unroll
  for (int r = 0; r < 4; ++r) {
    float s2 = 0.f;
#pragma unroll
    for (int ct = 0; ct < 4; ++ct) s2 = fmaf(acc[ct][r] + uk2[ct], xr[r][ct], s2);
    nkp[r] = s2;
  }
  // ---- Zv
#pragma unroll
  for (int ct = 0; ct < 4; ++ct) acc[ct] = z4;
  product5<3>(wsu, lane, xa0, xa1, acc);
#pragma unroll
  for (int r = 0; r < 4; ++r) {
    float s2 = 0.f, p2 = 0.f;
#pragma unroll
    for (int ct = 0; ct < 4; ++ct) {
      s2 = fmaf(acc[ct][r] + uv2[ct], xr[r][ct], s2);
      p2 = fmaf(pqv[ct], xr[r][ct], p2);
    }
    nvp[r] = s2;
    pqp[r] = p2;
  }

  // ---- reduce over the 16-lane column group; norms + row bias
  float invq[4], pqc[4];
#pragma unroll
  for (int r = 0; r < 4; ++r) {
    float a0 = nqp[r], a1 = nkp[r], a2 = nvp[r], a3 = pqp[r];
#pragma unroll
    for (int dd = 1; dd < 16; dd <<= 1) {
      a0 += __shfl_xor(a0, dd); a1 += __shfl_xor(a1, dd);
      a2 += __shfl_xor(a2, dd); a3 += __shfl_xor(a3, dd);
    }
    invq[r] = rsqrtf(a0 + sq);
    pqc[r] = a3 + c0;
    if (lc == 0) {
      nrmW[4 * g + r]      = rsqrtf(a1 + sk2);
      nrmW[16 + 4 * g + r] = rsqrtf(a2 + sv2);
    }
  }

  // ---- T~ = xs@A_qk + pk; restage as bf16 A-frags (overlays xsb, now dead)
  float pkv[4];
#pragma unroll
  for (int ct = 0; ct < 4; ++ct) pkv[ct] = ws[WS_PK + 16 * ct + lc];
#pragma unroll
  for (int ct = 0; ct < 4; ++ct) { f32x4 v = {pkv[ct], pkv[ct], pkv[ct], pkv[ct]}; acc[ct] = v; }
  product5<0>(wsu, lane, xa0, xa1, acc);
#pragma unroll
  for (int r = 0; r < 4; ++r)
#pragma unroll
    for (int ct = 0; ct < 4; ++ct) {
      const int c = 16 * ct + lc, i = 4 * g + r;
      *(unsigned short*)(P + (c >> 5) * 1024 + (((c >> 3) & 3) * 16 + i) * 16 + (c & 7) * 2)
          = f2bf(acc[ct][r]);
    }

  // ---- scores: S = T~ @ xs^T + pqc (B-frag of xs^T == A-frag of xs)
  const short8v ta0 = *(const short8v*)(P + lane * 16);
  const short8v ta1 = *(const short8v*)(P + 1024 + lane * 16);
  f32x4 sv = {pqc[0], pqc[1], pqc[2], pqc[3]};
  sv = mfma16(ta0, xa0, sv);
  sv = mfma16(ta1, xa1, sv);

  // ---- Yv = xs@M_vo + rvo (independent of softmax; overlaps MFMA pipe)
  float rvo[4];
#pragma unroll
  for (int ct = 0; ct < 4; ++ct) rvo[ct] = ws[WS_RVO + 16 * ct + lc];
#pragma unroll
  for (int ct = 0; ct < 4; ++ct) { f32x4 v = {rvo[ct], rvo[ct], rvo[ct], rvo[ct]}; acc[ct] = v; }
  product5<4>(wsu, lane, xa0, xa1, acc);

  // ---- softmax over j (=lc) per row r, fold 1/|V_j|; stage P A-frags
  const float ikj = nrmW[lc], ivj = nrmW[16 + lc];
  float sc0 = sv[0] * invq[0] * ikj;
  float sc1 = sv[1] * invq[1] * ikj;
  float sc2 = sv[2] * invq[2] * ikj;
  float sc3 = sv[3] * invq[3] * ikj;
  float m0 = sc0, m1 = sc1, m2 = sc2, m3 = sc3;
#pragma unroll
  for (int dd = 1; dd < 16; dd <<= 1) {
    m0 = fmaxf(m0, __shfl_xor(m0, dd)); m1 = fmaxf(m1, __shfl_xor(m1, dd));
    m2 = fmaxf(m2, __shfl_xor(m2, dd)); m3 = fmaxf(m3, __shfl_xor(m3, dd));
  }
  float e0 = __expf(sc0 - m0), e1 = __expf(sc1 - m1), e2 = __expf(sc2 - m2), e3 = __expf(sc3 - m3);
  float u0 = e0, u1 = e1, u2 = e2, u3 = e3;
#pragma unroll
  for (int dd = 1; dd < 16; dd <<= 1) {
    u0 += __shfl_xor(u0, dd); u1 += __shfl_xor(u1, dd);
    u2 += __shfl_xor(u2, dd); u3 += __shfl_xor(u3, dd);
  }
  const float w0 = e0 / u0 * ivj, w1 = e1 / u1 * ivj, w2 = e2 / u2 * ivj, w3 = e3 / u3 * ivj;
  {
    char* pt = P + PT_OFF + ((lc >> 3) * 16 + 4 * g) * 16 + (lc & 7) * 2;
    *(unsigned short*)(pt)      = f2bf(w0);
    *(unsigned short*)(pt + 16) = f2bf(w1);
    *(unsigned short*)(pt + 32) = f2bf(w2);
    *(unsigned short*)(pt + 48) = f2bf(w3);
  }

  // ---- stage Yv as bf16 B-frags (k = j < 16 -> lanes 0..31 only)
#pragma unroll
  for (int r = 0; r < 4; ++r) {
    const int j = 4 * g + r;
    char* yt = P + YT_OFF + ((j >> 3) * 16 + lc) * 16 + (j & 7) * 2;
#pragma unroll
    for (int ct = 0; ct < 4; ++ct)
      *(unsigned short*)(yt + ct * 512) = f2bf(acc[ct][r]);
  }

  // ---- PV + bias + residual (acc init = bo + resid), D-layout output
  float bov[4];
#pragma unroll
  for (int ct = 0; ct < 4; ++ct) bov[ct] = bo_g[16 * ct + lc];
  short8v pa = {0, 0, 0, 0, 0, 0, 0, 0};
  if (lane < 32) pa = *(const short8v*)(P + PT_OFF + lane * 16);
  f32x4 o[4];
#pragma unroll
  for (int ct = 0; ct < 4; ++ct) {
    f32x4 v = {bov[ct] + xr[0][ct], bov[ct] + xr[1][ct], bov[ct] + xr[2][ct], bov[ct] + xr[3][ct]};
    o[ct] = v;
  }
#pragma unroll
  for (int ct = 0; ct < 4; ++ct) {
    short8v yb = {0, 0, 0, 0, 0, 0, 0, 0};
    if (lane < 32) yb = *(const short8v*)(P + YT_OFF + ct * 512 + lane * 16);
    o[ct] = mfma16(pa, yb, o[ct]);
  }

  // ---- stage final fp32 [16][68] (overlays frag buffers, all dead)
#pragma unroll
  for (int ct = 0; ct < 4; ++ct)
#pragma unroll
    for (int r = 0; r < 4; ++r)
      *(float*)(P + (4 * g + r) * 272 + (16 * ct + lc) * 4) = o[ct][r];

  __syncthreads();
  {  // coalesced flush
    const int px = t & 7, cc = t >> 3;
    float* ob = out + gbase + px;
    const char* rb = lds + px * RPX;
#pragma unroll
    for (int f = 0; f < 16; ++f)
      ob[(size_t)(f * 64 + cc) * 4096] = *(const float*)(rb + f * 272 + cc * 4);
  }
}

extern "C" void kernel_launch(void* const* d_in, const int* in_sizes, int n_in,
                              void* d_out, int out_size, void* d_ws, size_t ws_size,
                              hipStream_t stream) {
  const float* x  = (const float*)d_in[0];
  const float* Wq = (const float*)d_in[1];
  const float* bq = (const float*)d_in[2];
  const float* Wk = (const float*)d_in[3];
  const float* bk = (const float*)d_in[4];
  const float* Wv = (const float*)d_in[5];
  const float* bv = (const float*)d_in[6];
  const float* Wo = (const float*)d_in[7];
  const float* bo = (const float*)d_in[8];
  float* out = (float*)d_out;
  float* ws  = (float*)d_ws;
  (void)in_sizes; (void)n_in; (void)out_size; (void)ws_size;

  k1<<<82, 256, 0, stream>>>(Wq, bq, Wk, bk, Wv, bv, Wo, ws);
  k2_main<<<1024, 512, 0, stream>>>(x, ws, bo, out);
}

// Round 6
// 137.494 us; speedup vs baseline: 2.1870x; 1.0056x over previous
//
#include <hip/hip_runtime.h>

typedef __attribute__((ext_vector_type(8))) short short8v;
typedef __attribute__((ext_vector_type(4))) float f32x4;

// ---------------- workspace layout ----------------
// ws[0 .. 10239] (floats) = bf16 fragment table for 5 matrices (40960 B):
//   shorts idx = ((m*2+kt)*4+ct)*512 + lane*8 + jj
//   holds M_m[k = kt*32 + sigma(lane,jj)][c = ct*16 + (lane&15)]
// m: 0=A_qk(WqWk^T) 1=G_q(WqWq^T) 2=G_k 3=G_v 4=M_vo(Wv@Wo)
#define WS_PQ  20480   // Wq@bk [64]
#define WS_PK  20544   // Wk@bq [64]
#define WS_UQ  20608   // Wq@bq
#define WS_UK  20672   // Wk@bk
#define WS_UV  20736   // Wv@bv
#define WS_RVO 20800   // bv@Wo [64]
#define WS_SC  20864   // c0=bq.bk, |bq|^2, |bk|^2, |bv|^2
#define WS_PE  20992   // pe[16][64]

#define RPX    4640    // per-pixel LDS region bytes (290*16, de-aliased vs 128)
#define PT_OFF 2064    // P-tilde A-frags (32 lanes * 16B)
#define YT_OFF 2576    // Yv B-frags (4 ct * 32 lanes * 16B)
#define NRM_OFF (8*RPX)
#define TAB_OFF 38144  // bf16 B-frag table staged in LDS (40960 B)

__device__ __forceinline__ unsigned short f2bf(float f) {
  unsigned u = __float_as_uint(f);
  u += 0x7fffu + ((u >> 16) & 1u);          // RNE
  return (unsigned short)(u >> 16);
}
__device__ __forceinline__ float bf2f(unsigned short h) {
  return __uint_as_float(((unsigned)h) << 16);
}
__device__ __forceinline__ f32x4 mfma16(short8v a, short8v b, f32x4 c) {
  return __builtin_amdgcn_mfma_f32_16x16x32_bf16(a, b, c, 0, 0, 0);
}

// ---------------- K1: fully wave-parallel precompute ----------------
// wave-jobs: 0..319  = matrix rows (m = wid>>6, a = wid&63), lane = output col
//            320..324 = vectors v0..v4 (lane = output row)
//            325      = rvo (lane = output col, Wo coalesced)
//            326      = 4 scalars (lane-parallel dot + reduce)
//            327      = positional-encoding table
__global__ __launch_bounds__(256) void k1(
    const float* __restrict__ Wq, const float* __restrict__ bq,
    const float* __restrict__ Wk, const float* __restrict__ bk,
    const float* __restrict__ Wv, const float* __restrict__ bv,
    const float* __restrict__ Wo, float* __restrict__ ws)
{
  const int lane = threadIdx.x & 63;
  const int wid  = (blockIdx.x << 2) | (threadIdx.x >> 6);
  unsigned short* wsu = (unsigned short*)ws;

  if (wid < 320) {  // M_m[a][c=lane] = dot over d=0..511
    const int m = wid >> 6, a = wid & 63;
    float a0 = 0.f, a1 = 0.f, a2 = 0.f, a3 = 0.f;
    if (m < 4) {
      const float* L = (m <= 1) ? Wq : (m == 2) ? Wk : Wv;
      const float* R = (m == 1) ? Wq : (m == 3) ? Wv : Wk;  // m0,m2 -> Wk
      const float* Lr = L + a * 512;
      const float* Rr = R + lane * 512;
#pragma unroll 4
      for (int d = 0; d < 512; d += 4) {
        const float4 l4 = *(const float4*)(Lr + d);
        const float4 r4 = *(const float4*)(Rr + d);
        a0 = fmaf(l4.x, r4.x, a0); a1 = fmaf(l4.y, r4.y, a1);
        a2 = fmaf(l4.z, r4.z, a2); a3 = fmaf(l4.w, r4.w, a3);
      }
    } else {        // M_vo[a][c] = sum_d Wv[a][d] * Wo[d][c], coalesced Wo
      const float* Lr = Wv + a * 512;
#pragma unroll 4
      for (int d = 0; d < 512; d += 4) {
        const float4 l4 = *(const float4*)(Lr + d);
        a0 = fmaf(l4.x, Wo[(d + 0) * 64 + lane], a0);
        a1 = fmaf(l4.y, Wo[(d + 1) * 64 + lane], a1);
        a2 = fmaf(l4.z, Wo[(d + 2) * 64 + lane], a2);
        a3 = fmaf(l4.w, Wo[(d + 3) * 64 + lane], a3);
      }
    }
    const float p = (a0 + a1) + (a2 + a3);
    const int c = lane;
    wsu[((m * 2 + (a >> 5)) * 4 + (c >> 4)) * 512
        + (((a >> 3) & 3) * 16 + (c & 15)) * 8 + (a & 7)] = f2bf(p);
    return;
  }

  if (wid < 325) {  // vectors: out[a=lane] = dot(L_row(a), r)
    const int v = wid - 320;
    const float* L = (v == 0 || v == 2) ? Wq : (v == 1 || v == 3) ? Wk : Wv;
    const float* r = (v == 0 || v == 3) ? bk : (v == 1 || v == 2) ? bq : bv;
    const int dst = (v == 0) ? WS_PQ : (v == 1) ? WS_PK : (v == 2) ? WS_UQ
                  : (v == 3) ? WS_UK : WS_UV;
    const float* Lr = L + lane * 512;
    float a0 = 0.f, a1 = 0.f, a2 = 0.f, a3 = 0.f;
#pragma unroll 4
    for (int d = 0; d < 512; d += 4) {
      const float4 l4 = *(const float4*)(Lr + d);
      const float4 r4 = *(const float4*)(r + d);
      a0 = fmaf(l4.x, r4.x, a0); a1 = fmaf(l4.y, r4.y, a1);
      a2 = fmaf(l4.z, r4.z, a2); a3 = fmaf(l4.w, r4.w, a3);
    }
    ws[dst + lane] = (a0 + a1) + (a2 + a3);
    return;
  }

  if (wid == 325) {  // rvo[c=lane] = sum_d bv[d] * Wo[d][c]
    float a0 = 0.f, a1 = 0.f, a2 = 0.f, a3 = 0.f;
#pragma unroll 4
    for (int d = 0; d < 512; d += 4) {
      const float4 b4 = *(const float4*)(bv + d);
      a0 = fmaf(b4.x, Wo[(d + 0) * 64 + lane], a0);
      a1 = fmaf(b4.y, Wo[(d + 1) * 64 + lane], a1);
      a2 = fmaf(b4.z, Wo[(d + 2) * 64 + lane], a2);
      a3 = fmaf(b4.w, Wo[(d + 3) * 64 + lane], a3);
    }
    ws[WS_RVO + lane] = (a0 + a1) + (a2 + a3);
    return;
  }

  if (wid == 326) {  // scalars: c0=bq.bk, |bq|^2, |bk|^2, |bv|^2
#pragma unroll
    for (int s = 0; s < 4; ++s) {
      const float* u  = (s <= 1) ? bq : (s == 2) ? bk : bv;
      const float* vv = (s == 0 || s == 2) ? bk : (s == 1) ? bq : bv;
      float p = 0.f;
#pragma unroll
      for (int dd = 0; dd < 8; ++dd) p = fmaf(u[lane + dd * 64], vv[lane + dd * 64], p);
#pragma unroll
      for (int dd = 1; dd < 64; dd <<= 1) p += __shfl_xor(p, dd);
      if (lane == 0) ws[WS_SC + s] = p;
    }
    return;
  }

  if (wid == 327) {  // positional encoding
    for (int idx = lane; idx < 1024; idx += 64) {
      int f = idx >> 6, ch = idx & 63;
      float div = __expf(-(float)(ch & ~1) * 0.14391156510303f);  // ln(1e4)/64
      float arg = (float)f * div;
      ws[WS_PE + idx] = (ch & 1) ? cosf(arg) : sinf(arg);
    }
  }
}

// load 8 B-frags of matrix MM from the LDS table; 2 MFMAs into each col-tile
template<int MM>
__device__ __forceinline__ void product5(const char* tab, int lane,
                                         short8v xa0, short8v xa1, f32x4 (&acc)[4]) {
  const char* base = tab + MM * 8192 + lane * 16;
  const short8v b00 = *(const short8v*)(base);
  const short8v b01 = *(const short8v*)(base + 1024);
  const short8v b02 = *(const short8v*)(base + 2048);
  const short8v b03 = *(const short8v*)(base + 3072);
  const short8v b10 = *(const short8v*)(base + 4096);
  const short8v b11 = *(const short8v*)(base + 5120);
  const short8v b12 = *(const short8v*)(base + 6144);
  const short8v b13 = *(const short8v*)(base + 7168);
  acc[0] = mfma16(xa0, b00, acc[0]);
  acc[1] = mfma16(xa0, b01, acc[1]);
  acc[2] = mfma16(xa0, b02, acc[2]);
  acc[3] = mfma16(xa0, b03, acc[3]);
  acc[0] = mfma16(xa1, b10, acc[0]);
  acc[1] = mfma16(xa1, b11, acc[1]);
  acc[2] = mfma16(xa1, b12, acc[2]);
  acc[3] = mfma16(xa1, b13, acc[3]);
}

// ---------------- K2: fused main kernel, 1 wave = 1 pixel ----------------
__global__ __launch_bounds__(512, 4) void k2_main(
    const float* __restrict__ x, const float* __restrict__ ws,
    const float* __restrict__ bo_g, float* __restrict__ out)
{
  __shared__ uint4 lds4[4944];   // 38144 (pixel regions + nrm) + 40960 (table) B
  char* lds = (char*)lds4;

  const int t = threadIdx.x;
  const int bid = blockIdx.x;
  // XCD-pair swizzle: blocks sharing a 64B input line land on the same XCD
  const int pb = (bid & ~15) | (((bid & 7) << 1) | ((bid >> 3) & 1));
  const int n0 = pb * 8;
  const size_t gbase = (size_t)(n0 >> 12) * 4194304 + (n0 & 4095);

  {  // stage the 40 KB B-frag table into LDS (kills the per-wave L2 re-reads)
    uint4* td = (uint4*)(lds + TAB_OFF);
    const uint4* ts = (const uint4*)ws;
#pragma unroll
    for (int i = 0; i < 5; ++i) td[t + i * 512] = ts[t + i * 512];
  }

  {  // cooperative stage: xs = x + pe -> bf16 A-fragment-packed LDS
    const int px = t & 7, cc = t >> 3;
    const float* xb = x + gbase + px;
    char* wb = lds + px * RPX + (cc >> 5) * 1024 + (((cc >> 3) & 3) * 16) * 16 + (cc & 7) * 2;
#pragma unroll
    for (int f = 0; f < 16; ++f) {
      float v = xb[(size_t)(f * 64 + cc) * 4096] + ws[WS_PE + f * 64 + cc];
      *(unsigned short*)(wb + f * 16) = f2bf(v);
    }
  }
  __syncthreads();

  const int w = t >> 6, lane = t & 63, g = lane >> 4, lc = lane & 15;
  char* P = lds + w * RPX;
  float* nrmW = (float*)(lds + NRM_OFF) + w * 32;
  const char* tab = lds + TAB_OFF;

  // xs A-fragments (also reused as B-operand for the score MFMA)
  const short8v xa0 = *(const short8v*)(P + lane * 16);
  const short8v xa1 = *(const short8v*)(P + 1024 + lane * 16);

  // per-lane xs values at this lane's D-layout positions (i=4g+r, c=16ct+lc)
  float xr[4][4];
#pragma unroll
  for (int r = 0; r < 4; ++r)
#pragma unroll
    for (int ct = 0; ct < 4; ++ct) {
      const int c = 16 * ct + lc, i = 4 * g + r;
      xr[r][ct] = bf2f(*(const unsigned short*)(
          P + (c >> 5) * 1024 + (((c >> 3) & 3) * 16 + i) * 16 + (c & 7) * 2));
    }

  float uq2[4], uk2[4], uv2[4], pqv[4];
#pragma unroll
  for (int ct = 0; ct < 4; ++ct) {
    const int c = 16 * ct + lc;
    uq2[ct] = 2.f * ws[WS_UQ + c];
    uk2[ct] = 2.f * ws[WS_UK + c];
    uv2[ct] = 2.f * ws[WS_UV + c];
    pqv[ct] = ws[WS_PQ + c];
  }
  const float c0 = ws[WS_SC], sq = ws[WS_SC + 1], sk2 = ws[WS_SC + 2], sv2 = ws[WS_SC + 3];

  const f32x4 z4 = {0.f, 0.f, 0.f, 0.f};
  f32x4 acc[4];
  float nqp[4], nkp[4], nvp[4], pqp[4];

  // ---- Zq = xs@G_q -> |Q| partials
#pragma unroll
  for (int ct = 0; ct < 4; ++ct) acc[ct] = z4;
  product5<1>(tab, lane, xa0, xa1, acc);
#pragma unroll
  for (int r = 0; r < 4; ++r) {
    float s2 = 0.f;
#pragma unroll
    for (int ct = 0; ct < 4; ++ct) s2 = fmaf(acc[ct][r] + uq2[ct], xr[r][ct], s2);
    nqp[r] = s2;
  }
  // ---- Zk
#pragma unroll
  for (int ct = 0; ct < 4; ++ct) acc[ct] = z4;
  product5<2>(tab, lane, xa0, xa1, acc);
#pragma unroll
  for (int r = 0; r < 4; ++r) {
    float s2 = 0.f;
#pragma unroll
    for (int ct = 0; ct < 4; ++ct) s2 = fmaf(acc[ct][r] + uk2[ct], xr[r][ct], s2);
    nkp[r] = s2;
  }
  // ---- Zv
#pragma unroll
  for (int ct = 0; ct < 4; ++ct) acc[ct] = z4;
  product5<3>(tab, lane, xa0, xa1, acc);
#pragma unroll
  for (int r = 0; r < 4; ++r) {
    float s2 = 0.f, p2 = 0.f;
#pragma unroll
    for (int ct = 0; ct < 4; ++ct) {
      s2 = fmaf(acc[ct][r] + uv2[ct], xr[r][ct], s2);
      p2 = fmaf(pqv[ct], xr[r][ct], p2);
    }
    nvp[r] = s2;
    pqp[r] = p2;
  }

  // ---- reduce over the 16-lane column group; norms + row bias
  float invq[4], pqc[4];
#pragma unroll
  for (int r = 0; r < 4; ++r) {
    float a0 = nqp[r], a1 = nkp[r], a2 = nvp[r], a3 = pqp[r];
#pragma unroll
    for (int dd = 1; dd < 16; dd <<= 1) {
      a0 += __shfl_xor(a0, dd); a1 += __shfl_xor(a1, dd);
      a2 += __shfl_xor(a2, dd); a3 += __shfl_xor(a3, dd);
    }
    invq[r] = rsqrtf(a0 + sq);
    pqc[r] = a3 + c0;
    if (lc == 0) {
      nrmW[4 * g + r]      = rsqrtf(a1 + sk2);
      nrmW[16 + 4 * g + r] = rsqrtf(a2 + sv2);
    }
  }

  // ---- T~ = xs@A_qk + pk; restage as bf16 A-frags (overlays xsb, now dead)
  float pkv[4];
#pragma unroll
  for (int ct = 0; ct < 4; ++ct) pkv[ct] = ws[WS_PK + 16 * ct + lc];
#pragma unroll
  for (int ct = 0; ct < 4; ++ct) { f32x4 v = {pkv[ct], pkv[ct], pkv[ct], pkv[ct]}; acc[ct] = v; }
  product5<0>(tab, lane, xa0, xa1, acc);
#pragma unroll
  for (int r = 0; r < 4; ++r)
#pragma unroll
    for (int ct = 0; ct < 4; ++ct) {
      const int c = 16 * ct + lc, i = 4 * g + r;
      *(unsigned short*)(P + (c >> 5) * 1024 + (((c >> 3) & 3) * 16 + i) * 16 + (c & 7) * 2)
          = f2bf(acc[ct][r]);
    }

  // ---- scores: S = T~ @ xs^T + pqc (B-frag of xs^T == A-frag of xs)
  const short8v ta0 = *(const short8v*)(P + lane * 16);
  const short8v ta1 = *(const short8v*)(P + 1024 + lane * 16);
  f32x4 sv = {pqc[0], pqc[1], pqc[2], pqc[3]};
  sv = mfma16(ta0, xa0, sv);
  sv = mfma16(ta1, xa1, sv);

  // ---- Yv = xs@M_vo + rvo (independent of softmax; overlaps MFMA pipe)
  float rvo[4];
#pragma unroll
  for (int ct = 0; ct < 4; ++ct) rvo[ct] = ws[WS_RVO + 16 * ct + lc];
#pragma unroll
  for (int ct = 0; ct < 4; ++ct) { f32x4 v = {rvo[ct], rvo[ct], rvo[ct], rvo[ct]}; acc[ct] = v; }
  product5<4>(tab, lane, xa0, xa1, acc);

  // ---- softmax over j (=lc) per row r, fold 1/|V_j|; stage P A-frags
  const float ikj = nrmW[lc], ivj = nrmW[16 + lc];
  float sc0 = sv[0] * invq[0] * ikj;
  float sc1 = sv[1] * invq[1] * ikj;
  float sc2 = sv[2] * invq[2] * ikj;
  float sc3 = sv[3] * invq[3] * ikj;
  float m0 = sc0, m1 = sc1, m2 = sc2, m3 = sc3;
#pragma unroll
  for (int dd = 1; dd < 16; dd <<= 1) {
    m0 = fmaxf(m0, __shfl_xor(m0, dd)); m1 = fmaxf(m1, __shfl_xor(m1, dd));
    m2 = fmaxf(m2, __shfl_xor(m2, dd)); m3 = fmaxf(m3, __shfl_xor(m3, dd));
  }
  float e0 = __expf(sc0 - m0), e1 = __expf(sc1 - m1), e2 = __expf(sc2 - m2), e3 = __expf(sc3 - m3);
  float u0 = e0, u1 = e1, u2 = e2, u3 = e3;
#pragma unroll
  for (int dd = 1; dd < 16; dd <<= 1) {
    u0 += __shfl_xor(u0, dd); u1 += __shfl_xor(u1, dd);
    u2 += __shfl_xor(u2, dd); u3 += __shfl_xor(u3, dd);
  }
  const float w0 = e0 / u0 * ivj, w1 = e1 / u1 * ivj, w2 = e2 / u2 * ivj, w3 = e3 / u3 * ivj;
  {
    char* pt = P + PT_OFF + ((lc >> 3) * 16 + 4 * g) * 16 + (lc & 7) * 2;
    *(unsigned short*)(pt)      = f2bf(w0);
    *(unsigned short*)(pt + 16) = f2bf(w1);
    *(unsigned short*)(pt + 32) = f2bf(w2);
    *(unsigned short*)(pt + 48) = f2bf(w3);
  }

  // ---- stage Yv as bf16 B-frags (k = j < 16 -> lanes 0..31 only)
#pragma unroll
  for (int r = 0; r < 4; ++r) {
    const int j = 4 * g + r;
    char* yt = P + YT_OFF + ((j >> 3) * 16 + lc) * 16 + (j & 7) * 2;
#pragma unroll
    for (int ct = 0; ct < 4; ++ct)
      *(unsigned short*)(yt + ct * 512) = f2bf(acc[ct][r]);
  }

  // ---- PV + bias + residual (acc init = bo + resid), D-layout output
  float bov[4];
#pragma unroll
  for (int ct = 0; ct < 4; ++ct) bov[ct] = bo_g[16 * ct + lc];
  short8v pa = {0, 0, 0, 0, 0, 0, 0, 0};
  if (lane < 32) pa = *(const short8v*)(P + PT_OFF + lane * 16);
  f32x4 o[4];
#pragma unroll
  for (int ct = 0; ct < 4; ++ct) {
    f32x4 v = {bov[ct] + xr[0][ct], bov[ct] + xr[1][ct], bov[ct] + xr[2][ct], bov[ct] + xr[3][ct]};
    o[ct] = v;
  }
#pragma unroll
  for (int ct = 0; ct < 4; ++ct) {
    short8v yb = {0, 0, 0, 0, 0, 0, 0, 0};
    if (lane < 32) yb = *(const short8v*)(P + YT_OFF + ct * 512 + lane * 16);
    o[ct] = mfma16(pa, yb, o[ct]);
  }

  // ---- stage final fp32 [16][68] (overlays frag buffers, all dead)
#pragma unroll
  for (int ct = 0; ct < 4; ++ct)
#pragma unroll
    for (int r = 0; r < 4; ++r)
      *(float*)(P + (4 * g + r) * 272 + (16 * ct + lc) * 4) = o[ct][r];

  __syncthreads();
  {  // coalesced flush
    const int px = t & 7, cc = t >> 3;
    float* ob = out + gbase + px;
    const char* rb = lds + px * RPX;
#pragma unroll
    for (int f = 0; f < 16; ++f)
      ob[(size_t)(f * 64 + cc) * 4096] = *(const float*)(rb + f * 272 + cc * 4);
  }
}

extern "C" void kernel_launch(void* const* d_in, const int* in_sizes, int n_in,
                              void* d_out, int out_size, void* d_ws, size_t ws_size,
                              hipStream_t stream) {
  const float* x  = (const float*)d_in[0];
  const float* Wq = (const float*)d_in[1];
  const float* bq = (const float*)d_in[2];
  const float* Wk = (const float*)d_in[3];
  const float* bk = (const float*)d_in[4];
  const float* Wv = (const float*)d_in[5];
  const float* bv = (const float*)d_in[6];
  const float* Wo = (const float*)d_in[7];
  const float* bo = (const float*)d_in[8];
  float* out = (float*)d_out;
  float* ws  = (float*)d_ws;
  (void)in_sizes; (void)n_in; (void)out_size; (void)ws_size;

  k1<<<82, 256, 0, stream>>>(Wq, bq, Wk, bk, Wv, bv, Wo, ws);
  k2_main<<<1024, 512, 0, stream>>>(x, ws, bo, out);
}